// Round 1
// baseline (553.869 us; speedup 1.0000x reference)
//
#include <hip/hip_runtime.h>

#define VOCAB 100000
#define DIM   512
#define BATCH 4096
#define SEQ   200
#define HID   256
#define OUTN  20

// ---------------------------------------------------------------------------
// Kernel 1: embedding gather + mean/max reduce over SEQ.
// One block per batch row. 128 threads, each owns one float4 column slice
// (128 * 4 = 512 = DIM). Each s-iteration is one coalesced 2KB row read.
// ---------------------------------------------------------------------------
__global__ __launch_bounds__(128) void k_reduce(
    const float* __restrict__ emb, const int* __restrict__ x,
    const int* __restrict__ lengths, float* __restrict__ rep)
{
    const int b = blockIdx.x;
    const int t = threadIdx.x;

    __shared__ int sidx[SEQ];
    for (int i = t; i < SEQ; i += 128) sidx[i] = x[b * SEQ + i];
    __syncthreads();

    const float4* embv = (const float4*)emb;
    float4 s = make_float4(0.f, 0.f, 0.f, 0.f);
    float4 m = make_float4(-1e30f, -1e30f, -1e30f, -1e30f);

#pragma unroll 4
    for (int i = 0; i < SEQ; ++i) {
        const float4 v = embv[(size_t)sidx[i] * (DIM / 4) + t];
        s.x += v.x; s.y += v.y; s.z += v.z; s.w += v.w;
        m.x = fmaxf(m.x, v.x); m.y = fmaxf(m.y, v.y);
        m.z = fmaxf(m.z, v.z); m.w = fmaxf(m.w, v.w);
    }

    const float inv = 1.0f / (float)lengths[b];
    float4 mean = make_float4(s.x * inv, s.y * inv, s.z * inv, s.w * inv);

    float4* repv = (float4*)rep;
    const size_t rowBase = (size_t)b * (2 * DIM / 4);
    repv[rowBase + t]             = mean;   // cols [0, 512)
    repv[rowBase + (DIM / 4) + t] = m;      // cols [512, 1024)
}

// ---------------------------------------------------------------------------
// Kernel 2: h = relu(rep @ W1 + b1)
// rep [BATCH, 1024] row-major, W1 [1024, 256] row-major, h [BATCH, 256].
// 64x64 block tile, BK=16, 256 threads, 4x4 per-thread microtile (fp32).
// ---------------------------------------------------------------------------
#define BM 64
#define BN 64
#define BK 16

__global__ __launch_bounds__(256) void k_gemm1(
    const float* __restrict__ A, const float* __restrict__ B,
    const float* __restrict__ bias, float* __restrict__ C)
{
    const int K = 2 * DIM;  // 1024
    const int bx = blockIdx.x;   // N tile index (0..3)
    const int by = blockIdx.y;   // M tile index (0..63)
    const int tid = threadIdx.x;
    const int tx = tid & 15;     // M direction (4 rows each)
    const int ty = tid >> 4;     // N direction (4 cols each)

    __shared__ float As[BK][BM];   // As[k][m] (transposed on store)
    __shared__ float Bs[BK][BN];

    float acc[4][4] = {};

    const int rowBase = by * BM;
    const int colBase = bx * BN;

    // A load: thread -> one float4 along K. r = tid/4 (0..63), kq = tid%4.
    const int ar  = tid >> 2;
    const int akq = tid & 3;
    // B load: thread -> one float4 along N. k = tid/16, nq = tid%16.
    const int bk  = tid >> 4;
    const int bnq = tid & 15;

    const float4* A4 = (const float4*)A;
    const float4* B4 = (const float4*)B;

    for (int k0 = 0; k0 < K; k0 += BK) {
        const float4 av = A4[(size_t)(rowBase + ar) * (K / 4) + (k0 >> 2) + akq];
        const float4 bv = B4[(size_t)(k0 + bk) * (HID / 4) + (colBase >> 2) + bnq];

        __syncthreads();  // previous iteration's reads done before overwrite
        As[akq * 4 + 0][ar] = av.x;
        As[akq * 4 + 1][ar] = av.y;
        As[akq * 4 + 2][ar] = av.z;
        As[akq * 4 + 3][ar] = av.w;
        *(float4*)&Bs[bk][bnq * 4] = bv;
        __syncthreads();

#pragma unroll
        for (int k = 0; k < BK; ++k) {
            const float4 a = *(const float4*)&As[k][tx * 4];
            const float4 b = *(const float4*)&Bs[k][ty * 4];
            acc[0][0] += a.x * b.x; acc[0][1] += a.x * b.y;
            acc[0][2] += a.x * b.z; acc[0][3] += a.x * b.w;
            acc[1][0] += a.y * b.x; acc[1][1] += a.y * b.y;
            acc[1][2] += a.y * b.z; acc[1][3] += a.y * b.w;
            acc[2][0] += a.z * b.x; acc[2][1] += a.z * b.y;
            acc[2][2] += a.z * b.z; acc[2][3] += a.z * b.w;
            acc[3][0] += a.w * b.x; acc[3][1] += a.w * b.y;
            acc[3][2] += a.w * b.z; acc[3][3] += a.w * b.w;
        }
    }

    // Epilogue: bias + relu, float4 stores (cols are consecutive).
    const int col0 = colBase + ty * 4;
    const float4 bb = *(const float4*)&bias[col0];
#pragma unroll
    for (int i = 0; i < 4; ++i) {
        const int r = rowBase + tx * 4 + i;
        float4 v;
        v.x = fmaxf(acc[i][0] + bb.x, 0.f);
        v.y = fmaxf(acc[i][1] + bb.y, 0.f);
        v.z = fmaxf(acc[i][2] + bb.z, 0.f);
        v.w = fmaxf(acc[i][3] + bb.w, 0.f);
        *(float4*)&C[(size_t)r * HID + col0] = v;
    }
}

// ---------------------------------------------------------------------------
// Kernel 3: logits = h @ W2 + b2
// h [BATCH, 256], W2 [256, 20], out [BATCH, 20]. 32 rows per block via LDS.
// ---------------------------------------------------------------------------
#define R3 32
#define HPAD 260   // 256 + 4 pad (keeps float4 alignment, breaks bank stride)

__global__ __launch_bounds__(256) void k_gemm2(
    const float* __restrict__ H, const float* __restrict__ W2,
    const float* __restrict__ b2, float* __restrict__ outp)
{
    __shared__ float sh[R3 * HPAD];
    __shared__ float sw[HID * OUTN];
    __shared__ float sb[OUTN];

    const int t = threadIdx.x;
    const int rowBase = blockIdx.x * R3;

    const float4* H4 = (const float4*)H;
    for (int i = t; i < R3 * (HID / 4); i += 256) {   // 2048 float4
        const int r  = i >> 6;       // / (HID/4)
        const int c4 = i & 63;
        *(float4*)&sh[r * HPAD + c4 * 4] = H4[(size_t)(rowBase + r) * (HID / 4) + c4];
    }
    for (int i = t; i < HID * OUTN; i += 256) sw[i] = W2[i];
    if (t < OUTN) sb[t] = b2[t];
    __syncthreads();

    for (int o = t; o < R3 * OUTN; o += 256) {
        const int r = o / OUTN;
        const int c = o - r * OUTN;
        float acc = sb[c];
#pragma unroll 8
        for (int k = 0; k < HID; ++k)
            acc += sh[r * HPAD + k] * sw[k * OUTN + c];
        outp[(size_t)(rowBase + r) * OUTN + c] = acc;
    }
}

// ---------------------------------------------------------------------------
extern "C" void kernel_launch(void* const* d_in, const int* in_sizes, int n_in,
                              void* d_out, int out_size, void* d_ws, size_t ws_size,
                              hipStream_t stream)
{
    const float* emb     = (const float*)d_in[0];
    const float* W1      = (const float*)d_in[1];
    const float* b1      = (const float*)d_in[2];
    const float* W2      = (const float*)d_in[3];
    const float* b2      = (const float*)d_in[4];
    const int*   x       = (const int*)d_in[5];
    const int*   lengths = (const int*)d_in[6];
    // d_in[7] (bows) unused by the model.

    float* out = (float*)d_out;
    float* rep = (float*)d_ws;                         // [BATCH, 1024] = 16.8 MB
    float* h   = rep + (size_t)BATCH * 2 * DIM;        // [BATCH, 256]  =  4.2 MB

    k_reduce<<<BATCH, 128, 0, stream>>>(emb, x, lengths, rep);
    k_gemm1<<<dim3(HID / BN, BATCH / BM), 256, 0, stream>>>(rep, W1, b1, h);
    k_gemm2<<<BATCH / R3, 256, 0, stream>>>(h, W2, b2, out);
}

// Round 2
// 522.133 us; speedup vs baseline: 1.0608x; 1.0608x over previous
//
#include <hip/hip_runtime.h>

#define VOCAB 100000
#define DIM   512
#define BATCH 4096
#define SEQ   200
#define HID   256
#define OUTN  20

// ---------------------------------------------------------------------------
// Kernel 1: embedding gather + mean/max reduce over SEQ.
// One block per batch row. 128 threads, each owns one float4 column slice.
// 8-way unrolled: 8 independent gathers in flight per thread, two accumulator
// sets to shorten the dependence chains.
// ---------------------------------------------------------------------------
__global__ __launch_bounds__(128) void k_reduce(
    const float* __restrict__ emb, const int* __restrict__ x,
    const int* __restrict__ lengths, float* __restrict__ rep)
{
    const int b = blockIdx.x;
    const int t = threadIdx.x;

    __shared__ int sidx[SEQ];
    for (int i = t; i < SEQ; i += 128) sidx[i] = x[b * SEQ + i];
    __syncthreads();

    const float4* __restrict__ embv = (const float4*)emb + t;

    float4 s0 = make_float4(0.f, 0.f, 0.f, 0.f);
    float4 s1 = make_float4(0.f, 0.f, 0.f, 0.f);
    float4 m0 = make_float4(-1e30f, -1e30f, -1e30f, -1e30f);
    float4 m1 = make_float4(-1e30f, -1e30f, -1e30f, -1e30f);

    // SEQ = 200 = 25 * 8
    for (int i = 0; i < SEQ; i += 8) {
        const float4* p0 = embv + (size_t)sidx[i + 0] * (DIM / 4);
        const float4* p1 = embv + (size_t)sidx[i + 1] * (DIM / 4);
        const float4* p2 = embv + (size_t)sidx[i + 2] * (DIM / 4);
        const float4* p3 = embv + (size_t)sidx[i + 3] * (DIM / 4);
        const float4* p4 = embv + (size_t)sidx[i + 4] * (DIM / 4);
        const float4* p5 = embv + (size_t)sidx[i + 5] * (DIM / 4);
        const float4* p6 = embv + (size_t)sidx[i + 6] * (DIM / 4);
        const float4* p7 = embv + (size_t)sidx[i + 7] * (DIM / 4);
        const float4 v0 = *p0;
        const float4 v1 = *p1;
        const float4 v2 = *p2;
        const float4 v3 = *p3;
        const float4 v4 = *p4;
        const float4 v5 = *p5;
        const float4 v6 = *p6;
        const float4 v7 = *p7;
        s0.x += v0.x; s0.y += v0.y; s0.z += v0.z; s0.w += v0.w;
        m0.x = fmaxf(m0.x, v0.x); m0.y = fmaxf(m0.y, v0.y);
        m0.z = fmaxf(m0.z, v0.z); m0.w = fmaxf(m0.w, v0.w);
        s1.x += v1.x; s1.y += v1.y; s1.z += v1.z; s1.w += v1.w;
        m1.x = fmaxf(m1.x, v1.x); m1.y = fmaxf(m1.y, v1.y);
        m1.z = fmaxf(m1.z, v1.z); m1.w = fmaxf(m1.w, v1.w);
        s0.x += v2.x; s0.y += v2.y; s0.z += v2.z; s0.w += v2.w;
        m0.x = fmaxf(m0.x, v2.x); m0.y = fmaxf(m0.y, v2.y);
        m0.z = fmaxf(m0.z, v2.z); m0.w = fmaxf(m0.w, v2.w);
        s1.x += v3.x; s1.y += v3.y; s1.z += v3.z; s1.w += v3.w;
        m1.x = fmaxf(m1.x, v3.x); m1.y = fmaxf(m1.y, v3.y);
        m1.z = fmaxf(m1.z, v3.z); m1.w = fmaxf(m1.w, v3.w);
        s0.x += v4.x; s0.y += v4.y; s0.z += v4.z; s0.w += v4.w;
        m0.x = fmaxf(m0.x, v4.x); m0.y = fmaxf(m0.y, v4.y);
        m0.z = fmaxf(m0.z, v4.z); m0.w = fmaxf(m0.w, v4.w);
        s1.x += v5.x; s1.y += v5.y; s1.z += v5.z; s1.w += v5.w;
        m1.x = fmaxf(m1.x, v5.x); m1.y = fmaxf(m1.y, v5.y);
        m1.z = fmaxf(m1.z, v5.z); m1.w = fmaxf(m1.w, v5.w);
        s0.x += v6.x; s0.y += v6.y; s0.z += v6.z; s0.w += v6.w;
        m0.x = fmaxf(m0.x, v6.x); m0.y = fmaxf(m0.y, v6.y);
        m0.z = fmaxf(m0.z, v6.z); m0.w = fmaxf(m0.w, v6.w);
        s1.x += v7.x; s1.y += v7.y; s1.z += v7.z; s1.w += v7.w;
        m1.x = fmaxf(m1.x, v7.x); m1.y = fmaxf(m1.y, v7.y);
        m1.z = fmaxf(m1.z, v7.z); m1.w = fmaxf(m1.w, v7.w);
    }

    const float inv = 1.0f / (float)lengths[b];
    float4 mean;
    mean.x = (s0.x + s1.x) * inv;
    mean.y = (s0.y + s1.y) * inv;
    mean.z = (s0.z + s1.z) * inv;
    mean.w = (s0.w + s1.w) * inv;
    float4 mx;
    mx.x = fmaxf(m0.x, m1.x); mx.y = fmaxf(m0.y, m1.y);
    mx.z = fmaxf(m0.z, m1.z); mx.w = fmaxf(m0.w, m1.w);

    float4* repv = (float4*)rep;
    const size_t rowBase = (size_t)b * (2 * DIM / 4);
    repv[rowBase + t]             = mean;   // cols [0, 512)
    repv[rowBase + (DIM / 4) + t] = mx;     // cols [512, 1024)
}

// ---------------------------------------------------------------------------
// Kernel 2: h = relu(rep @ W1 + b1)
// rep [BATCH, 1024] row-major, W1 [1024, 256] row-major, h [BATCH, 256].
// 64x64 block tile, BK=16, 256 threads, 4x4 microtile, register
// double-buffering: tile k+1 global loads issue before the 16 FMA steps of
// tile k, so vmcnt waits are hidden behind compute, not exposed at barriers.
// ---------------------------------------------------------------------------
#define BM 64
#define BN 64
#define BK 16

__global__ __launch_bounds__(256) void k_gemm1(
    const float* __restrict__ A, const float* __restrict__ B,
    const float* __restrict__ bias, float* __restrict__ C)
{
    const int K = 2 * DIM;  // 1024
    const int bx = blockIdx.x;
    const int by = blockIdx.y;
    const int tid = threadIdx.x;
    const int tx = tid & 15;     // M direction (4 rows each)
    const int ty = tid >> 4;     // N direction (4 cols each)

    __shared__ float As[BK][BM];
    __shared__ float Bs[BK][BN];

    float acc[4][4] = {};

    const int rowBase = by * BM;
    const int colBase = bx * BN;

    const int ar  = tid >> 2;    // 0..63
    const int akq = tid & 3;     // 0..3
    const int bk  = tid >> 4;    // 0..15
    const int bnq = tid & 15;    // 0..15

    const float4* A4 = (const float4*)A;
    const float4* B4 = (const float4*)B;

    // Prologue: load tile 0 into registers.
    float4 av = A4[(size_t)(rowBase + ar) * (K / 4) + akq];
    float4 bv = B4[(size_t)bk * (HID / 4) + (colBase >> 2) + bnq];

    for (int k0 = 0; k0 < K; k0 += BK) {
        __syncthreads();   // all waves done reading LDS of previous tile
        As[akq * 4 + 0][ar] = av.x;
        As[akq * 4 + 1][ar] = av.y;
        As[akq * 4 + 2][ar] = av.z;
        As[akq * 4 + 3][ar] = av.w;
        *(float4*)&Bs[bk][bnq * 4] = bv;
        __syncthreads();

        if (k0 + BK < K) {  // prefetch next tile; wait lands after 16 FMA steps
            av = A4[(size_t)(rowBase + ar) * (K / 4) + ((k0 + BK) >> 2) + akq];
            bv = B4[(size_t)(k0 + BK + bk) * (HID / 4) + (colBase >> 2) + bnq];
        }

#pragma unroll
        for (int k = 0; k < BK; ++k) {
            const float4 a = *(const float4*)&As[k][tx * 4];
            const float4 b = *(const float4*)&Bs[k][ty * 4];
            acc[0][0] += a.x * b.x; acc[0][1] += a.x * b.y;
            acc[0][2] += a.x * b.z; acc[0][3] += a.x * b.w;
            acc[1][0] += a.y * b.x; acc[1][1] += a.y * b.y;
            acc[1][2] += a.y * b.z; acc[1][3] += a.y * b.w;
            acc[2][0] += a.z * b.x; acc[2][1] += a.z * b.y;
            acc[2][2] += a.z * b.z; acc[2][3] += a.z * b.w;
            acc[3][0] += a.w * b.x; acc[3][1] += a.w * b.y;
            acc[3][2] += a.w * b.z; acc[3][3] += a.w * b.w;
        }
    }

    const int col0 = colBase + ty * 4;
    const float4 bb = *(const float4*)&bias[col0];
#pragma unroll
    for (int i = 0; i < 4; ++i) {
        const int r = rowBase + tx * 4 + i;
        float4 v;
        v.x = fmaxf(acc[i][0] + bb.x, 0.f);
        v.y = fmaxf(acc[i][1] + bb.y, 0.f);
        v.z = fmaxf(acc[i][2] + bb.z, 0.f);
        v.w = fmaxf(acc[i][3] + bb.w, 0.f);
        *(float4*)&C[(size_t)r * HID + col0] = v;
    }
}

// ---------------------------------------------------------------------------
// Kernel 3: logits = h @ W2 + b2
// ---------------------------------------------------------------------------
#define R3 32
#define HPAD 260

__global__ __launch_bounds__(256) void k_gemm2(
    const float* __restrict__ H, const float* __restrict__ W2,
    const float* __restrict__ b2, float* __restrict__ outp)
{
    __shared__ float sh[R3 * HPAD];
    __shared__ float sw[HID * OUTN];
    __shared__ float sb[OUTN];

    const int t = threadIdx.x;
    const int rowBase = blockIdx.x * R3;

    const float4* H4 = (const float4*)H;
    for (int i = t; i < R3 * (HID / 4); i += 256) {
        const int r  = i >> 6;
        const int c4 = i & 63;
        *(float4*)&sh[r * HPAD + c4 * 4] = H4[(size_t)(rowBase + r) * (HID / 4) + c4];
    }
    for (int i = t; i < HID * OUTN; i += 256) sw[i] = W2[i];
    if (t < OUTN) sb[t] = b2[t];
    __syncthreads();

    for (int o = t; o < R3 * OUTN; o += 256) {
        const int r = o / OUTN;
        const int c = o - r * OUTN;
        float acc = sb[c];
#pragma unroll 8
        for (int k = 0; k < HID; ++k)
            acc += sh[r * HPAD + k] * sw[k * OUTN + c];
        outp[(size_t)(rowBase + r) * OUTN + c] = acc;
    }
}

// ---------------------------------------------------------------------------
extern "C" void kernel_launch(void* const* d_in, const int* in_sizes, int n_in,
                              void* d_out, int out_size, void* d_ws, size_t ws_size,
                              hipStream_t stream)
{
    const float* emb     = (const float*)d_in[0];
    const float* W1      = (const float*)d_in[1];
    const float* b1      = (const float*)d_in[2];
    const float* W2      = (const float*)d_in[3];
    const float* b2      = (const float*)d_in[4];
    const int*   x       = (const int*)d_in[5];
    const int*   lengths = (const int*)d_in[6];

    float* out = (float*)d_out;
    float* rep = (float*)d_ws;                         // [BATCH, 1024]
    float* h   = rep + (size_t)BATCH * 2 * DIM;        // [BATCH, 256]

    k_reduce<<<BATCH, 128, 0, stream>>>(emb, x, lengths, rep);
    k_gemm1<<<dim3(HID / BN, BATCH / BM), 256, 0, stream>>>(rep, W1, b1, h);
    k_gemm2<<<BATCH / R3, 256, 0, stream>>>(h, W2, b2, out);
}

// Round 3
// 487.045 us; speedup vs baseline: 1.1372x; 1.0720x over previous
//
#include <hip/hip_runtime.h>
#include <hip/hip_bf16.h>

#define VOCAB 100000
#define DIM   512
#define BATCH 4096
#define SEQ   200
#define HID   256
#define OUTN  20

typedef __attribute__((ext_vector_type(8))) short short8;
typedef __attribute__((ext_vector_type(4))) float floatx4;

static __device__ __forceinline__ unsigned short f2bf(float f) {
    __hip_bfloat16 b = __float2bfloat16(f);
    return *(unsigned short*)&b;
}

// ---------------------------------------------------------------------------
// Kernel 1: embedding gather + mean/max reduce over SEQ. One block per batch
// row, 128 threads x float4 = 512 cols. Output rep in BF16 [BATCH, 1024].
// ---------------------------------------------------------------------------
__global__ __launch_bounds__(128) void k_reduce(
    const float* __restrict__ emb, const int* __restrict__ x,
    const int* __restrict__ lengths, unsigned short* __restrict__ repb)
{
    const int b = blockIdx.x;
    const int t = threadIdx.x;

    __shared__ int sidx[SEQ];
    for (int i = t; i < SEQ; i += 128) sidx[i] = x[b * SEQ + i];
    __syncthreads();

    const float4* embv = (const float4*)emb;
    float4 s = make_float4(0.f, 0.f, 0.f, 0.f);
    float4 m = make_float4(-1e30f, -1e30f, -1e30f, -1e30f);

#pragma unroll 4
    for (int i = 0; i < SEQ; ++i) {
        const float4 v = embv[(size_t)sidx[i] * (DIM / 4) + t];
        s.x += v.x; s.y += v.y; s.z += v.z; s.w += v.w;
        m.x = fmaxf(m.x, v.x); m.y = fmaxf(m.y, v.y);
        m.z = fmaxf(m.z, v.z); m.w = fmaxf(m.w, v.w);
    }

    const float inv = 1.0f / (float)lengths[b];

    unsigned long long mu =
          (unsigned long long)f2bf(s.x * inv)
        | ((unsigned long long)f2bf(s.y * inv) << 16)
        | ((unsigned long long)f2bf(s.z * inv) << 32)
        | ((unsigned long long)f2bf(s.w * inv) << 48);
    unsigned long long xu =
          (unsigned long long)f2bf(m.x)
        | ((unsigned long long)f2bf(m.y) << 16)
        | ((unsigned long long)f2bf(m.z) << 32)
        | ((unsigned long long)f2bf(m.w) << 48);

    unsigned short* row = repb + (size_t)b * (2 * DIM);
    *(unsigned long long*)(row + 4 * t)       = mu;   // cols [0,512)
    *(unsigned long long*)(row + DIM + 4 * t) = xu;   // cols [512,1024)
}

// ---------------------------------------------------------------------------
// Kernel 1b: W1 [1024, 256] fp32 -> W1T [256, 1024] bf16 (transpose+convert),
// so gemm1 B-fragments read contiguous k. 64x64 tiles via LDS.
// ---------------------------------------------------------------------------
__global__ __launch_bounds__(256) void k_w1t(
    const float* __restrict__ W1, unsigned short* __restrict__ W1T)
{
    __shared__ unsigned short s[64][65];
    const int n0 = blockIdx.x * 64;   // 4 blocks in n
    const int k0 = blockIdx.y * 64;   // 16 blocks in k
    const int t = threadIdx.x;

#pragma unroll
    for (int i = 0; i < 4; ++i) {
        const int kk = (t >> 4) + i * 16;          // 0..63
        const int cc = (t & 15) * 4;               // 0..60
        const float4 v = *(const float4*)&W1[(size_t)(k0 + kk) * HID + n0 + cc];
        s[cc + 0][kk] = f2bf(v.x);
        s[cc + 1][kk] = f2bf(v.y);
        s[cc + 2][kk] = f2bf(v.z);
        s[cc + 3][kk] = f2bf(v.w);
    }
    __syncthreads();

#pragma unroll
    for (int i = 0; i < 4; ++i) {
        const int nn = (t >> 4) + i * 16;          // 0..63
        const int kq = (t & 15) * 4;               // 0..60
        unsigned long long u =
              (unsigned long long)s[nn][kq + 0]
            | ((unsigned long long)s[nn][kq + 1] << 16)
            | ((unsigned long long)s[nn][kq + 2] << 32)
            | ((unsigned long long)s[nn][kq + 3] << 48);
        *(unsigned long long*)&W1T[(size_t)(n0 + nn) * (2 * DIM) + k0 + kq] = u;
    }
}

// ---------------------------------------------------------------------------
// Kernel 2: h = relu(rep @ W1 + b1) via bf16 MFMA 16x16x32, fp32 accum.
// rep bf16 [4096,1024], W1T bf16 [256,1024], h fp32 [4096,256].
// Block = 64x64 tile, 4 waves in 2x2; each wave 32x32 via 2x2 mfma tiles.
// Fragment maps (verified m89/m120): A[m=lane&15][k=(lane>>4)*8+j],
// B[n=lane&15][k=(lane>>4)*8+j], D: col=lane&15, row=(lane>>4)*4+reg.
// ---------------------------------------------------------------------------
__global__ __launch_bounds__(256) void k_gemm1(
    const unsigned short* __restrict__ repb,
    const unsigned short* __restrict__ w1t,
    const float* __restrict__ bias, float* __restrict__ h)
{
    const int K = 2 * DIM;               // 1024
    const int rowBase = blockIdx.y * 64; // M
    const int colBase = blockIdx.x * 64; // N
    const int tid  = threadIdx.x;
    const int lane = tid & 63;
    const int wv   = tid >> 6;           // 0..3
    const int wm   = wv & 1;             // wave M half
    const int wn   = wv >> 1;            // wave N half

    __shared__ unsigned short sA[64][32];
    __shared__ unsigned short sB[64][32];

    const int r  = tid >> 2;             // 0..63
    const int kq = tid & 3;              // 0..3  (8 bf16 each)

    const unsigned short* gA = repb + (size_t)(rowBase + r) * K + kq * 8;
    const unsigned short* gB = w1t  + (size_t)(colBase + r) * K + kq * 8;

    floatx4 acc[2][2] = {{{0.f,0.f,0.f,0.f},{0.f,0.f,0.f,0.f}},
                         {{0.f,0.f,0.f,0.f},{0.f,0.f,0.f,0.f}}};

    short8 pa = *(const short8*)gA;
    short8 pb = *(const short8*)gB;

    const int lm = lane & 15;            // m/n within 16-tile
    const int lq = lane >> 4;            // quad -> k chunk
    for (int k0 = 0; k0 < K; k0 += 32) {
        __syncthreads();
        *(short8*)&sA[r][kq * 8] = pa;
        *(short8*)&sB[r][kq * 8] = pb;
        __syncthreads();

        if (k0 + 32 < K) {
            pa = *(const short8*)(gA + k0 + 32);
            pb = *(const short8*)(gB + k0 + 32);
        }

        const short8 a0 = *(const short8*)&sA[wm * 32 + lm][lq * 8];
        const short8 a1 = *(const short8*)&sA[wm * 32 + 16 + lm][lq * 8];
        const short8 b0 = *(const short8*)&sB[wn * 32 + lm][lq * 8];
        const short8 b1 = *(const short8*)&sB[wn * 32 + 16 + lm][lq * 8];

        acc[0][0] = __builtin_amdgcn_mfma_f32_16x16x32_bf16(a0, b0, acc[0][0], 0, 0, 0);
        acc[0][1] = __builtin_amdgcn_mfma_f32_16x16x32_bf16(a0, b1, acc[0][1], 0, 0, 0);
        acc[1][0] = __builtin_amdgcn_mfma_f32_16x16x32_bf16(a1, b0, acc[1][0], 0, 0, 0);
        acc[1][1] = __builtin_amdgcn_mfma_f32_16x16x32_bf16(a1, b1, acc[1][1], 0, 0, 0);
    }

#pragma unroll
    for (int nt = 0; nt < 2; ++nt) {
        const int col = colBase + wn * 32 + nt * 16 + lm;
        const float bb = bias[col];
#pragma unroll
        for (int mt = 0; mt < 2; ++mt) {
#pragma unroll
            for (int rg = 0; rg < 4; ++rg) {
                const int row = rowBase + wm * 32 + mt * 16 + lq * 4 + rg;
                h[(size_t)row * HID + col] = fmaxf(acc[mt][nt][rg] + bb, 0.f);
            }
        }
    }
}

// ---------------------------------------------------------------------------
// Kernel 3: logits = h @ W2 + b2.  h fp32 [4096,256], W2 [256,20].
// ---------------------------------------------------------------------------
#define R3 32
#define HPAD 260

__global__ __launch_bounds__(256) void k_gemm2(
    const float* __restrict__ H, const float* __restrict__ W2,
    const float* __restrict__ b2, float* __restrict__ outp)
{
    __shared__ float sh[R3 * HPAD];
    __shared__ float sw[HID * OUTN];
    __shared__ float sb[OUTN];

    const int t = threadIdx.x;
    const int rowBase = blockIdx.x * R3;

    const float4* H4 = (const float4*)H;
    for (int i = t; i < R3 * (HID / 4); i += 256) {
        const int r  = i >> 6;
        const int c4 = i & 63;
        *(float4*)&sh[r * HPAD + c4 * 4] = H4[(size_t)(rowBase + r) * (HID / 4) + c4];
    }
    for (int i = t; i < HID * OUTN; i += 256) sw[i] = W2[i];
    if (t < OUTN) sb[t] = b2[t];
    __syncthreads();

    for (int o = t; o < R3 * OUTN; o += 256) {
        const int r = o / OUTN;
        const int c = o - r * OUTN;
        float acc = sb[c];
#pragma unroll 8
        for (int k = 0; k < HID; ++k)
            acc += sh[r * HPAD + k] * sw[k * OUTN + c];
        outp[(size_t)(rowBase + r) * OUTN + c] = acc;
    }
}

// ---------------------------------------------------------------------------
extern "C" void kernel_launch(void* const* d_in, const int* in_sizes, int n_in,
                              void* d_out, int out_size, void* d_ws, size_t ws_size,
                              hipStream_t stream)
{
    const float* emb     = (const float*)d_in[0];
    const float* W1      = (const float*)d_in[1];
    const float* b1      = (const float*)d_in[2];
    const float* W2      = (const float*)d_in[3];
    const float* b2      = (const float*)d_in[4];
    const int*   x       = (const int*)d_in[5];
    const int*   lengths = (const int*)d_in[6];

    float* out = (float*)d_out;

    unsigned short* repb = (unsigned short*)d_ws;                    // 8 MB
    unsigned short* w1t  = repb + (size_t)BATCH * 2 * DIM;           // 0.5 MB
    float* h = (float*)(w1t + (size_t)HID * 2 * DIM);                // 4 MB

    k_w1t<<<dim3(HID / 64, (2 * DIM) / 64), 256, 0, stream>>>(W1, w1t);
    k_reduce<<<BATCH, 128, 0, stream>>>(emb, x, lengths, repb);
    k_gemm1<<<dim3(HID / 64, BATCH / 64), 256, 0, stream>>>(repb, w1t, b1, h);
    k_gemm2<<<BATCH / R3, 256, 0, stream>>>(h, W2, b2, out);
}

// Round 4
// 441.884 us; speedup vs baseline: 1.2534x; 1.1022x over previous
//
#include <hip/hip_runtime.h>
#include <hip/hip_bf16.h>

#define VOCAB 100000
#define DIM   512
#define BATCH 4096
#define SEQ   200
#define HID   256
#define OUTN  20

typedef __attribute__((ext_vector_type(8))) short short8;
typedef __attribute__((ext_vector_type(4))) float floatx4;

static __device__ __forceinline__ unsigned short f2bf(float f) {
    __hip_bfloat16 b = __float2bfloat16(f);
    return *(unsigned short*)&b;
}
static __device__ __forceinline__ float bf2f(unsigned short u) {
    unsigned int v = (unsigned int)u << 16;
    return *(float*)&v;
}

// ---------------------------------------------------------------------------
// Kernel 0: emb_table fp32 [VOCAB, 512] -> bf16 [VOCAB, 512]. Pure stream.
// ---------------------------------------------------------------------------
__global__ __launch_bounds__(256) void k_cvt(
    const float* __restrict__ src, unsigned short* __restrict__ dst)
{
    const int n8 = VOCAB * DIM / 8;          // 6.4M groups of 8
    int i = blockIdx.x * 256 + threadIdx.x;
    const int stride = gridDim.x * 256;
    const float4* s4 = (const float4*)src;
    short8* d8 = (short8*)dst;
    for (; i < n8; i += stride) {
        const float4 a = s4[2 * i];
        const float4 b = s4[2 * i + 1];
        short8 o;
        o[0] = (short)f2bf(a.x); o[1] = (short)f2bf(a.y);
        o[2] = (short)f2bf(a.z); o[3] = (short)f2bf(a.w);
        o[4] = (short)f2bf(b.x); o[5] = (short)f2bf(b.y);
        o[6] = (short)f2bf(b.z); o[7] = (short)f2bf(b.w);
        d8[i] = o;
    }
}

// ---------------------------------------------------------------------------
// Kernel 1 (fast path): gather+reduce over bf16 table. One block per batch
// row, 128 threads = 2 waves; each wave reads full 1KB rows (64 lanes x 16B)
// for its half of the tokens; cross-wave reduce via LDS. rep out in bf16.
// ---------------------------------------------------------------------------
__global__ __launch_bounds__(128) void k_reduce_bf(
    const unsigned short* __restrict__ embb, const int* __restrict__ x,
    const int* __restrict__ lengths, unsigned short* __restrict__ repb)
{
    const int b = blockIdx.x;
    const int t = threadIdx.x;
    const int w = t >> 6;            // wave 0/1
    const int lane = t & 63;

    __shared__ int sidx[SEQ];
    for (int i = t; i < SEQ; i += 128) sidx[i] = x[b * SEQ + i];
    __syncthreads();

    float s[8] = {0.f, 0.f, 0.f, 0.f, 0.f, 0.f, 0.f, 0.f};
    float m[8] = {-1e30f, -1e30f, -1e30f, -1e30f, -1e30f, -1e30f, -1e30f, -1e30f};

    const unsigned short* base = embb + lane * 8;   // lane's 8 columns
    const int i0 = w * (SEQ / 2);

#pragma unroll 4
    for (int i = i0; i < i0 + SEQ / 2; ++i) {
        const short8 v = *(const short8*)(base + (size_t)sidx[i] * DIM);
#pragma unroll
        for (int j = 0; j < 8; ++j) {
            const float f = bf2f((unsigned short)v[j]);
            s[j] += f;
            m[j] = fmaxf(m[j], f);
        }
    }

    __shared__ float red[2][2][DIM];   // [wave][sum|max][col] = 8 KB
#pragma unroll
    for (int j = 0; j < 8; ++j) {
        red[w][0][lane * 8 + j] = s[j];
        red[w][1][lane * 8 + j] = m[j];
    }
    __syncthreads();

    // 128 threads x 4 columns each
    const float inv = 1.0f / (float)lengths[b];
    const int c0 = t * 4;
    unsigned long long mu = 0, xu = 0;
#pragma unroll
    for (int j = 0; j < 4; ++j) {
        const float sv = red[0][0][c0 + j] + red[1][0][c0 + j];
        const float mv = fmaxf(red[0][1][c0 + j], red[1][1][c0 + j]);
        mu |= (unsigned long long)f2bf(sv * inv) << (16 * j);
        xu |= (unsigned long long)f2bf(mv)       << (16 * j);
    }
    unsigned short* row = repb + (size_t)b * (2 * DIM);
    *(unsigned long long*)(row + c0)       = mu;   // cols [0,512)
    *(unsigned long long*)(row + DIM + c0) = xu;   // cols [512,1024)
}

// ---------------------------------------------------------------------------
// Kernel 1 (fallback path, fp32 table): as in R3.
// ---------------------------------------------------------------------------
__global__ __launch_bounds__(128) void k_reduce(
    const float* __restrict__ emb, const int* __restrict__ x,
    const int* __restrict__ lengths, unsigned short* __restrict__ repb)
{
    const int b = blockIdx.x;
    const int t = threadIdx.x;

    __shared__ int sidx[SEQ];
    for (int i = t; i < SEQ; i += 128) sidx[i] = x[b * SEQ + i];
    __syncthreads();

    const float4* embv = (const float4*)emb;
    float4 s = make_float4(0.f, 0.f, 0.f, 0.f);
    float4 m = make_float4(-1e30f, -1e30f, -1e30f, -1e30f);

#pragma unroll 4
    for (int i = 0; i < SEQ; ++i) {
        const float4 v = embv[(size_t)sidx[i] * (DIM / 4) + t];
        s.x += v.x; s.y += v.y; s.z += v.z; s.w += v.w;
        m.x = fmaxf(m.x, v.x); m.y = fmaxf(m.y, v.y);
        m.z = fmaxf(m.z, v.z); m.w = fmaxf(m.w, v.w);
    }

    const float inv = 1.0f / (float)lengths[b];
    unsigned long long mu =
          (unsigned long long)f2bf(s.x * inv)
        | ((unsigned long long)f2bf(s.y * inv) << 16)
        | ((unsigned long long)f2bf(s.z * inv) << 32)
        | ((unsigned long long)f2bf(s.w * inv) << 48);
    unsigned long long xu =
          (unsigned long long)f2bf(m.x)
        | ((unsigned long long)f2bf(m.y) << 16)
        | ((unsigned long long)f2bf(m.z) << 32)
        | ((unsigned long long)f2bf(m.w) << 48);

    unsigned short* row = repb + (size_t)b * (2 * DIM);
    *(unsigned long long*)(row + 4 * t)       = mu;
    *(unsigned long long*)(row + DIM + 4 * t) = xu;
}

// ---------------------------------------------------------------------------
// Kernel 1b: W1 [1024, 256] fp32 -> W1T [256, 1024] bf16 (transpose+convert).
// ---------------------------------------------------------------------------
__global__ __launch_bounds__(256) void k_w1t(
    const float* __restrict__ W1, unsigned short* __restrict__ W1T)
{
    __shared__ unsigned short s[64][65];
    const int n0 = blockIdx.x * 64;
    const int k0 = blockIdx.y * 64;
    const int t = threadIdx.x;

#pragma unroll
    for (int i = 0; i < 4; ++i) {
        const int kk = (t >> 4) + i * 16;
        const int cc = (t & 15) * 4;
        const float4 v = *(const float4*)&W1[(size_t)(k0 + kk) * HID + n0 + cc];
        s[cc + 0][kk] = f2bf(v.x);
        s[cc + 1][kk] = f2bf(v.y);
        s[cc + 2][kk] = f2bf(v.z);
        s[cc + 3][kk] = f2bf(v.w);
    }
    __syncthreads();

#pragma unroll
    for (int i = 0; i < 4; ++i) {
        const int nn = (t >> 4) + i * 16;
        const int kq = (t & 15) * 4;
        unsigned long long u =
              (unsigned long long)s[nn][kq + 0]
            | ((unsigned long long)s[nn][kq + 1] << 16)
            | ((unsigned long long)s[nn][kq + 2] << 32)
            | ((unsigned long long)s[nn][kq + 3] << 48);
        *(unsigned long long*)&W1T[(size_t)(n0 + nn) * (2 * DIM) + k0 + kq] = u;
    }
}

// ---------------------------------------------------------------------------
// Kernel 2: h = relu(rep @ W1 + b1) via bf16 MFMA 16x16x32, fp32 accum.
// LDS padded +8 shorts/row: fragment ds_reads go 8-way -> 2-way (free).
// ---------------------------------------------------------------------------
#define APAD 40   // 32 + 8

__global__ __launch_bounds__(256) void k_gemm1(
    const unsigned short* __restrict__ repb,
    const unsigned short* __restrict__ w1t,
    const float* __restrict__ bias, float* __restrict__ h)
{
    const int K = 2 * DIM;               // 1024
    const int rowBase = blockIdx.y * 64; // M
    const int colBase = blockIdx.x * 64; // N
    const int tid  = threadIdx.x;
    const int lane = tid & 63;
    const int wv   = tid >> 6;
    const int wm   = wv & 1;
    const int wn   = wv >> 1;

    __shared__ unsigned short sA[64][APAD];
    __shared__ unsigned short sB[64][APAD];

    const int r  = tid >> 2;
    const int kq = tid & 3;

    const unsigned short* gA = repb + (size_t)(rowBase + r) * K + kq * 8;
    const unsigned short* gB = w1t  + (size_t)(colBase + r) * K + kq * 8;

    floatx4 acc[2][2] = {{{0.f,0.f,0.f,0.f},{0.f,0.f,0.f,0.f}},
                         {{0.f,0.f,0.f,0.f},{0.f,0.f,0.f,0.f}}};

    short8 pa = *(const short8*)gA;
    short8 pb = *(const short8*)gB;

    const int lm = lane & 15;
    const int lq = lane >> 4;
    for (int k0 = 0; k0 < K; k0 += 32) {
        __syncthreads();
        *(short8*)&sA[r][kq * 8] = pa;
        *(short8*)&sB[r][kq * 8] = pb;
        __syncthreads();

        if (k0 + 32 < K) {
            pa = *(const short8*)(gA + k0 + 32);
            pb = *(const short8*)(gB + k0 + 32);
        }

        const short8 a0 = *(const short8*)&sA[wm * 32 + lm][lq * 8];
        const short8 a1 = *(const short8*)&sA[wm * 32 + 16 + lm][lq * 8];
        const short8 b0 = *(const short8*)&sB[wn * 32 + lm][lq * 8];
        const short8 b1 = *(const short8*)&sB[wn * 32 + 16 + lm][lq * 8];

        acc[0][0] = __builtin_amdgcn_mfma_f32_16x16x32_bf16(a0, b0, acc[0][0], 0, 0, 0);
        acc[0][1] = __builtin_amdgcn_mfma_f32_16x16x32_bf16(a0, b1, acc[0][1], 0, 0, 0);
        acc[1][0] = __builtin_amdgcn_mfma_f32_16x16x32_bf16(a1, b0, acc[1][0], 0, 0, 0);
        acc[1][1] = __builtin_amdgcn_mfma_f32_16x16x32_bf16(a1, b1, acc[1][1], 0, 0, 0);
    }

#pragma unroll
    for (int nt = 0; nt < 2; ++nt) {
        const int col = colBase + wn * 32 + nt * 16 + lm;
        const float bb = bias[col];
#pragma unroll
        for (int mt = 0; mt < 2; ++mt) {
#pragma unroll
            for (int rg = 0; rg < 4; ++rg) {
                const int row = rowBase + wm * 32 + mt * 16 + lq * 4 + rg;
                h[(size_t)row * HID + col] = fmaxf(acc[mt][nt][rg] + bb, 0.f);
            }
        }
    }
}

// ---------------------------------------------------------------------------
// Kernel 3: logits = h @ W2 + b2.
// ---------------------------------------------------------------------------
#define R3 32
#define HPAD 260

__global__ __launch_bounds__(256) void k_gemm2(
    const float* __restrict__ H, const float* __restrict__ W2,
    const float* __restrict__ b2, float* __restrict__ outp)
{
    __shared__ float sh[R3 * HPAD];
    __shared__ float sw[HID * OUTN];
    __shared__ float sb[OUTN];

    const int t = threadIdx.x;
    const int rowBase = blockIdx.x * R3;

    const float4* H4 = (const float4*)H;
    for (int i = t; i < R3 * (HID / 4); i += 256) {
        const int r  = i >> 6;
        const int c4 = i & 63;
        *(float4*)&sh[r * HPAD + c4 * 4] = H4[(size_t)(rowBase + r) * (HID / 4) + c4];
    }
    for (int i = t; i < HID * OUTN; i += 256) sw[i] = W2[i];
    if (t < OUTN) sb[t] = b2[t];
    __syncthreads();

    for (int o = t; o < R3 * OUTN; o += 256) {
        const int r = o / OUTN;
        const int c = o - r * OUTN;
        float acc = sb[c];
#pragma unroll 8
        for (int k = 0; k < HID; ++k)
            acc += sh[r * HPAD + k] * sw[k * OUTN + c];
        outp[(size_t)(rowBase + r) * OUTN + c] = acc;
    }
}

// ---------------------------------------------------------------------------
extern "C" void kernel_launch(void* const* d_in, const int* in_sizes, int n_in,
                              void* d_out, int out_size, void* d_ws, size_t ws_size,
                              hipStream_t stream)
{
    const float* emb     = (const float*)d_in[0];
    const float* W1      = (const float*)d_in[1];
    const float* b1      = (const float*)d_in[2];
    const float* W2      = (const float*)d_in[3];
    const float* b2      = (const float*)d_in[4];
    const int*   x       = (const int*)d_in[5];
    const int*   lengths = (const int*)d_in[6];

    float* out = (float*)d_out;

    const size_t embbN = (size_t)VOCAB * DIM;            // bf16 elems, 102.4 MB
    const size_t repbN = (size_t)BATCH * 2 * DIM;        // bf16 elems,   8.4 MB
    const size_t w1tN  = (size_t)HID * 2 * DIM;          // bf16 elems,   0.5 MB
    const size_t hN    = (size_t)BATCH * HID;            // fp32 elems,   4.2 MB
    const size_t needFast = (embbN + repbN + w1tN) * 2 + hN * 4 + 256;

    if (ws_size >= needFast) {
        unsigned short* embb = (unsigned short*)d_ws;
        unsigned short* repb = embb + embbN;
        unsigned short* w1t  = repb + repbN;
        float* h = (float*)(w1t + w1tN);

        k_cvt<<<2048, 256, 0, stream>>>(emb, embb);
        k_w1t<<<dim3(HID / 64, (2 * DIM) / 64), 256, 0, stream>>>(W1, w1t);
        k_reduce_bf<<<BATCH, 128, 0, stream>>>(embb, x, lengths, repb);
        k_gemm1<<<dim3(HID / 64, BATCH / 64), 256, 0, stream>>>(repb, w1t, b1, h);
        k_gemm2<<<BATCH / R3, 256, 0, stream>>>(h, W2, b2, out);
    } else {
        unsigned short* repb = (unsigned short*)d_ws;
        unsigned short* w1t  = repb + repbN;
        float* h = (float*)(w1t + w1tN);

        k_w1t<<<dim3(HID / 64, (2 * DIM) / 64), 256, 0, stream>>>(W1, w1t);
        k_reduce<<<BATCH, 128, 0, stream>>>(emb, x, lengths, repb);
        k_gemm1<<<dim3(HID / 64, BATCH / 64), 256, 0, stream>>>(repb, w1t, b1, h);
        k_gemm2<<<BATCH / R3, 256, 0, stream>>>(h, W2, b2, out);
    }
}

// Round 6
// 424.887 us; speedup vs baseline: 1.3036x; 1.0400x over previous
//
#include <hip/hip_runtime.h>
#include <hip/hip_bf16.h>

#define VOCAB 100000
#define DIM   512
#define BATCH 4096
#define SEQ   200
#define HID   256
#define OUTN  20

typedef __attribute__((ext_vector_type(8))) short short8;
typedef __attribute__((ext_vector_type(4))) float floatx4;

static __device__ __forceinline__ unsigned short f2bf(float f) {
    __hip_bfloat16 b = __float2bfloat16(f);
    return *(unsigned short*)&b;
}
static __device__ __forceinline__ float bf2f(unsigned short u) {
    unsigned int v = (unsigned int)u << 16;
    return *(float*)&v;
}

// ---------------------------------------------------------------------------
// Kernel 0: emb_table fp32 [VOCAB, 512] -> bf16 [VOCAB, 512]. Pure stream.
// NT loads on the fp32 source (never re-read; keeps L2/L3 for the bf16
// table); normal stores so the bf16 table stays cache-resident for gather.
// ---------------------------------------------------------------------------
__global__ __launch_bounds__(256) void k_cvt(
    const float* __restrict__ src, unsigned short* __restrict__ dst)
{
    const int n8 = VOCAB * DIM / 8;          // 6.4M groups of 8
    int i = blockIdx.x * 256 + threadIdx.x;
    const int stride = gridDim.x * 256;
    const floatx4* s4 = (const floatx4*)src;   // native vector type for NT builtin
    short8* d8 = (short8*)dst;
    for (; i < n8; i += stride) {
        const floatx4 a = __builtin_nontemporal_load(&s4[2 * i]);
        const floatx4 b = __builtin_nontemporal_load(&s4[2 * i + 1]);
        short8 o;
        o[0] = (short)f2bf(a[0]); o[1] = (short)f2bf(a[1]);
        o[2] = (short)f2bf(a[2]); o[3] = (short)f2bf(a[3]);
        o[4] = (short)f2bf(b[0]); o[5] = (short)f2bf(b[1]);
        o[6] = (short)f2bf(b[2]); o[7] = (short)f2bf(b[3]);
        d8[i] = o;
    }
}

// ---------------------------------------------------------------------------
// Kernel 1: gather+reduce over bf16 table. One block per batch row,
// 256 threads = 4 waves; each wave reads full 1KB rows (64 lanes x 16B) for
// its quarter of the tokens; cross-wave reduce via LDS. rep out in bf16.
// ---------------------------------------------------------------------------
__global__ __launch_bounds__(256) void k_reduce_bf(
    const unsigned short* __restrict__ embb, const int* __restrict__ x,
    const int* __restrict__ lengths, unsigned short* __restrict__ repb)
{
    const int b = blockIdx.x;
    const int t = threadIdx.x;
    const int w = t >> 6;            // wave 0..3
    const int lane = t & 63;

    __shared__ int sidx[SEQ];
    for (int i = t; i < SEQ; i += 256) sidx[i] = x[b * SEQ + i];
    __syncthreads();

    float s[8] = {0.f, 0.f, 0.f, 0.f, 0.f, 0.f, 0.f, 0.f};
    float m[8] = {-1e30f, -1e30f, -1e30f, -1e30f, -1e30f, -1e30f, -1e30f, -1e30f};

    const unsigned short* base = embb + lane * 8;   // lane's 8 columns
    const int i0 = w * (SEQ / 4);

#pragma unroll 5
    for (int i = i0; i < i0 + SEQ / 4; ++i) {
        const short8 v = *(const short8*)(base + (size_t)sidx[i] * DIM);
#pragma unroll
        for (int j = 0; j < 8; ++j) {
            const float f = bf2f((unsigned short)v[j]);
            s[j] += f;
            m[j] = fmaxf(m[j], f);
        }
    }

    __shared__ float red[4][2][DIM];   // [wave][sum|max][col] = 16 KB
#pragma unroll
    for (int j = 0; j < 8; ++j) {
        red[w][0][lane * 8 + j] = s[j];
        red[w][1][lane * 8 + j] = m[j];
    }
    __syncthreads();

    // 256 threads x 2 columns each
    const float inv = 1.0f / (float)lengths[b];
    const int c0 = t * 2;
    unsigned int mu = 0, xu = 0;
#pragma unroll
    for (int j = 0; j < 2; ++j) {
        const float sv = red[0][0][c0 + j] + red[1][0][c0 + j]
                       + red[2][0][c0 + j] + red[3][0][c0 + j];
        const float mv = fmaxf(fmaxf(red[0][1][c0 + j], red[1][1][c0 + j]),
                               fmaxf(red[2][1][c0 + j], red[3][1][c0 + j]));
        mu |= (unsigned int)f2bf(sv * inv) << (16 * j);
        xu |= (unsigned int)f2bf(mv)       << (16 * j);
    }
    unsigned short* row = repb + (size_t)b * (2 * DIM);
    *(unsigned int*)(row + c0)       = mu;   // cols [0,512)
    *(unsigned int*)(row + DIM + c0) = xu;   // cols [512,1024)
}

// ---------------------------------------------------------------------------
// Kernel 1 (fallback path, fp32 table): gather direct.
// ---------------------------------------------------------------------------
__global__ __launch_bounds__(128) void k_reduce(
    const float* __restrict__ emb, const int* __restrict__ x,
    const int* __restrict__ lengths, unsigned short* __restrict__ repb)
{
    const int b = blockIdx.x;
    const int t = threadIdx.x;

    __shared__ int sidx[SEQ];
    for (int i = t; i < SEQ; i += 128) sidx[i] = x[b * SEQ + i];
    __syncthreads();

    const float4* embv = (const float4*)emb;
    float4 s = make_float4(0.f, 0.f, 0.f, 0.f);
    float4 m = make_float4(-1e30f, -1e30f, -1e30f, -1e30f);

#pragma unroll 4
    for (int i = 0; i < SEQ; ++i) {
        const float4 v = embv[(size_t)sidx[i] * (DIM / 4) + t];
        s.x += v.x; s.y += v.y; s.z += v.z; s.w += v.w;
        m.x = fmaxf(m.x, v.x); m.y = fmaxf(m.y, v.y);
        m.z = fmaxf(m.z, v.z); m.w = fmaxf(m.w, v.w);
    }

    const float inv = 1.0f / (float)lengths[b];
    unsigned long long mu =
          (unsigned long long)f2bf(s.x * inv)
        | ((unsigned long long)f2bf(s.y * inv) << 16)
        | ((unsigned long long)f2bf(s.z * inv) << 32)
        | ((unsigned long long)f2bf(s.w * inv) << 48);
    unsigned long long xu =
          (unsigned long long)f2bf(m.x)
        | ((unsigned long long)f2bf(m.y) << 16)
        | ((unsigned long long)f2bf(m.z) << 32)
        | ((unsigned long long)f2bf(m.w) << 48);

    unsigned short* row = repb + (size_t)b * (2 * DIM);
    *(unsigned long long*)(row + 4 * t)       = mu;
    *(unsigned long long*)(row + DIM + 4 * t) = xu;
}

// ---------------------------------------------------------------------------
// Kernel 1b: W1 [1024, 256] fp32 -> W1T [256, 1024] bf16 (transpose+convert).
// ---------------------------------------------------------------------------
__global__ __launch_bounds__(256) void k_w1t(
    const float* __restrict__ W1, unsigned short* __restrict__ W1T)
{
    __shared__ unsigned short s[64][65];
    const int n0 = blockIdx.x * 64;
    const int k0 = blockIdx.y * 64;
    const int t = threadIdx.x;

#pragma unroll
    for (int i = 0; i < 4; ++i) {
        const int kk = (t >> 4) + i * 16;
        const int cc = (t & 15) * 4;
        const float4 v = *(const float4*)&W1[(size_t)(k0 + kk) * HID + n0 + cc];
        s[cc + 0][kk] = f2bf(v.x);
        s[cc + 1][kk] = f2bf(v.y);
        s[cc + 2][kk] = f2bf(v.z);
        s[cc + 3][kk] = f2bf(v.w);
    }
    __syncthreads();

#pragma unroll
    for (int i = 0; i < 4; ++i) {
        const int nn = (t >> 4) + i * 16;
        const int kq = (t & 15) * 4;
        unsigned long long u =
              (unsigned long long)s[nn][kq + 0]
            | ((unsigned long long)s[nn][kq + 1] << 16)
            | ((unsigned long long)s[nn][kq + 2] << 32)
            | ((unsigned long long)s[nn][kq + 3] << 48);
        *(unsigned long long*)&W1T[(size_t)(n0 + nn) * (2 * DIM) + k0 + kq] = u;
    }
}

// ---------------------------------------------------------------------------
// Kernel 2: h = relu(rep @ W1 + b1) via bf16 MFMA 16x16x32, fp32 accum.
// ---------------------------------------------------------------------------
#define APAD 40   // 32 + 8

__global__ __launch_bounds__(256) void k_gemm1(
    const unsigned short* __restrict__ repb,
    const unsigned short* __restrict__ w1t,
    const float* __restrict__ bias, float* __restrict__ h)
{
    const int K = 2 * DIM;               // 1024
    const int rowBase = blockIdx.y * 64; // M
    const int colBase = blockIdx.x * 64; // N
    const int tid  = threadIdx.x;
    const int lane = tid & 63;
    const int wv   = tid >> 6;
    const int wm   = wv & 1;
    const int wn   = wv >> 1;

    __shared__ unsigned short sA[64][APAD];
    __shared__ unsigned short sB[64][APAD];

    const int r  = tid >> 2;
    const int kq = tid & 3;

    const unsigned short* gA = repb + (size_t)(rowBase + r) * K + kq * 8;
    const unsigned short* gB = w1t  + (size_t)(colBase + r) * K + kq * 8;

    floatx4 acc[2][2] = {{{0.f,0.f,0.f,0.f},{0.f,0.f,0.f,0.f}},
                         {{0.f,0.f,0.f,0.f},{0.f,0.f,0.f,0.f}}};

    short8 pa = *(const short8*)gA;
    short8 pb = *(const short8*)gB;

    const int lm = lane & 15;
    const int lq = lane >> 4;
    for (int k0 = 0; k0 < K; k0 += 32) {
        __syncthreads();
        *(short8*)&sA[r][kq * 8] = pa;
        *(short8*)&sB[r][kq * 8] = pb;
        __syncthreads();

        if (k0 + 32 < K) {
            pa = *(const short8*)(gA + k0 + 32);
            pb = *(const short8*)(gB + k0 + 32);
        }

        const short8 a0 = *(const short8*)&sA[wm * 32 + lm][lq * 8];
        const short8 a1 = *(const short8*)&sA[wm * 32 + 16 + lm][lq * 8];
        const short8 b0 = *(const short8*)&sB[wn * 32 + lm][lq * 8];
        const short8 b1 = *(const short8*)&sB[wn * 32 + 16 + lm][lq * 8];

        acc[0][0] = __builtin_amdgcn_mfma_f32_16x16x32_bf16(a0, b0, acc[0][0], 0, 0, 0);
        acc[0][1] = __builtin_amdgcn_mfma_f32_16x16x32_bf16(a0, b1, acc[0][1], 0, 0, 0);
        acc[1][0] = __builtin_amdgcn_mfma_f32_16x16x32_bf16(a1, b0, acc[1][0], 0, 0, 0);
        acc[1][1] = __builtin_amdgcn_mfma_f32_16x16x32_bf16(a1, b1, acc[1][1], 0, 0, 0);
    }

#pragma unroll
    for (int nt = 0; nt < 2; ++nt) {
        const int col = colBase + wn * 32 + nt * 16 + lm;
        const float bb = bias[col];
#pragma unroll
        for (int mt = 0; mt < 2; ++mt) {
#pragma unroll
            for (int rg = 0; rg < 4; ++rg) {
                const int row = rowBase + wm * 32 + mt * 16 + lq * 4 + rg;
                h[(size_t)row * HID + col] = fmaxf(acc[mt][nt][rg] + bb, 0.f);
            }
        }
    }
}

// ---------------------------------------------------------------------------
// Kernel 3: logits = h @ W2 + b2.  h fp32 [4096,256], W2 [256,20].
// Transposed W2 in LDS; float4 k-loop. Thread t -> row r = t&31,
// col-slot cs = t>>5 (0..7) covering cols {cs, cs+8, cs+16(<20)}.
// ---------------------------------------------------------------------------
#define R3 32
#define HP4 260   // 256 + 4 pad

__global__ __launch_bounds__(256) void k_gemm2(
    const float* __restrict__ H, const float* __restrict__ W2,
    const float* __restrict__ b2, float* __restrict__ outp)
{
    __shared__ float sh[R3][HP4];      // 33.3 KB
    __shared__ float swt[OUTN][HP4];   // 20.8 KB
    __shared__ float sb[OUTN];

    const int t = threadIdx.x;
    const int rowBase = blockIdx.x * R3;

    const float4* H4 = (const float4*)H;
    for (int i = t; i < R3 * (HID / 4); i += 256) {
        const int r  = i >> 6;
        const int c4 = i & 63;
        *(float4*)&sh[r][c4 * 4] = H4[(size_t)(rowBase + r) * (HID / 4) + c4];
    }
    // W2 [256][20] -> swt[20][256]; thread t = k row
    {
        const int k = t;  // 0..255
#pragma unroll
        for (int c = 0; c < OUTN; ++c) swt[c][k] = W2[k * OUTN + c];
    }
    if (t < OUTN) sb[t] = b2[t];
    __syncthreads();

    const int r  = t & 31;
    const int cs = t >> 5;          // 0..7
    float a0 = sb[cs], a1 = sb[cs + 8], a2 = (cs + 16 < OUTN) ? sb[cs + 16] : 0.f;
    float acc0 = 0.f, acc1 = 0.f, acc2 = 0.f;

#pragma unroll 8
    for (int k = 0; k < HID; k += 4) {
        const float4 a = *(const float4*)&sh[r][k];
        const float4 w0 = *(const float4*)&swt[cs][k];
        const float4 w1 = *(const float4*)&swt[cs + 8][k];
        acc0 += a.x * w0.x + a.y * w0.y + a.z * w0.z + a.w * w0.w;
        acc1 += a.x * w1.x + a.y * w1.y + a.z * w1.z + a.w * w1.w;
        if (cs + 16 < OUTN) {
            const float4 w2 = *(const float4*)&swt[cs + 16][k];
            acc2 += a.x * w2.x + a.y * w2.y + a.z * w2.z + a.w * w2.w;
        }
    }

    float* orow = outp + (size_t)(rowBase + r) * OUTN;
    orow[cs]     = acc0 + a0;
    orow[cs + 8] = acc1 + a1;
    if (cs + 16 < OUTN) orow[cs + 16] = acc2 + a2;
}

// ---------------------------------------------------------------------------
extern "C" void kernel_launch(void* const* d_in, const int* in_sizes, int n_in,
                              void* d_out, int out_size, void* d_ws, size_t ws_size,
                              hipStream_t stream)
{
    const float* emb     = (const float*)d_in[0];
    const float* W1      = (const float*)d_in[1];
    const float* b1      = (const float*)d_in[2];
    const float* W2      = (const float*)d_in[3];
    const float* b2      = (const float*)d_in[4];
    const int*   x       = (const int*)d_in[5];
    const int*   lengths = (const int*)d_in[6];

    float* out = (float*)d_out;

    const size_t embbN = (size_t)VOCAB * DIM;            // bf16 elems, 102.4 MB
    const size_t repbN = (size_t)BATCH * 2 * DIM;        // bf16 elems,   8.4 MB
    const size_t w1tN  = (size_t)HID * 2 * DIM;          // bf16 elems,   0.5 MB
    const size_t hN    = (size_t)BATCH * HID;            // fp32 elems,   4.2 MB
    const size_t needFast = (embbN + repbN + w1tN) * 2 + hN * 4 + 256;

    if (ws_size >= needFast) {
        unsigned short* embb = (unsigned short*)d_ws;
        unsigned short* repb = embb + embbN;
        unsigned short* w1t  = repb + repbN;
        float* h = (float*)(w1t + w1tN);

        k_cvt<<<2048, 256, 0, stream>>>(emb, embb);
        k_w1t<<<dim3(HID / 64, (2 * DIM) / 64), 256, 0, stream>>>(W1, w1t);
        k_reduce_bf<<<BATCH, 256, 0, stream>>>(embb, x, lengths, repb);
        k_gemm1<<<dim3(HID / 64, BATCH / 64), 256, 0, stream>>>(repb, w1t, b1, h);
        k_gemm2<<<BATCH / R3, 256, 0, stream>>>(h, W2, b2, out);
    } else {
        unsigned short* repb = (unsigned short*)d_ws;
        unsigned short* w1t  = repb + repbN;
        float* h = (float*)(w1t + w1tN);

        k_w1t<<<dim3(HID / 64, (2 * DIM) / 64), 256, 0, stream>>>(W1, w1t);
        k_reduce<<<BATCH, 128, 0, stream>>>(emb, x, lengths, repb);
        k_gemm1<<<dim3(HID / 64, BATCH / 64), 256, 0, stream>>>(repb, w1t, b1, h);
        k_gemm2<<<BATCH / R3, 256, 0, stream>>>(h, W2, b2, out);
    }
}